// Round 15
// baseline (6243.932 us; speedup 1.0000x reference)
//
#include <hip/hip_runtime.h>
#include <math.h>

// Problem dims
#define TT 2048
#define VV 1024
#define HH 2048
#define SS (VV + HH)        // 3072: row stride of Wf_w / Wb_w

// Geometry: 256 WGs x 512 threads, one WG per CU (forced by LDS pad).
#define NWGD 128            // workgroups per direction
#define BTH  512            // threads per workgroup (8 waves = 2/EU)
#define UPW  16             // hidden units per wg
#define KSL  32             // k-slices per unit
#define KPT  64             // k-elements per thread (per gate row)

#define NREP 16             // mailbox replicas (kills poll line contention)
#define MB_PAR (NREP * NWGD * 16)   // u32 per parity per dir = 32768 (128KB)

#define HL2W 68             // ushorts per h-row (136B: 2-way bank alias max)
#define HL2SZ (KSL * HL2W)  // 2176 ushorts per buffer

static_assert(NWGD * UPW == HH, "unit coverage");
static_assert(UPW * KSL == BTH, "thread coverage");
static_assert(KSL * KPT == HH, "k coverage");

typedef _Float16 half2_t __attribute__((ext_vector_type(2)));
typedef unsigned uint4v  __attribute__((ext_vector_type(4)));

#if defined(__has_builtin)
#if __has_builtin(__builtin_amdgcn_fdot2)
#define FDOT2(w, h, c) __builtin_amdgcn_fdot2((w), (h), (c), false)
#endif
#endif
#ifndef FDOT2
__device__ __forceinline__ float fdot2_asm(half2_t w, half2_t h, float c) {
    float r = c;
    asm volatile("v_dot2_f32_f16 %0, %1, %2, %0" : "+v"(r) : "v"(w), "v"(h));
    return r;
}
#define FDOT2(w, h, c) fdot2_asm((w), (h), (c))
#endif

__device__ __forceinline__ float sigmoidf_(float x) {
    return 1.0f / (1.0f + __expf(-x));
}

__device__ __forceinline__ float h2f(unsigned u) {
    return (float)__builtin_bit_cast(_Float16, (unsigned short)(u & 0xFFFFu));
}

// LDS-only barrier: VMEM (publish stores, prefetches) stays in flight.
// __syncthreads would emit s_waitcnt vmcnt(0) (r12 lesson).
#define LDS_BARRIER() asm volatile("s_waitcnt lgkmcnt(0)\n\ts_barrier" ::: "memory")

// Mailbox: [dir][parity][replica r<16][producer p<128][quad q<4] of 16B:
//   { h(4q..4q+3) as 4 x fp16 ; 0 ; tag = s+1 }
// Publish = wave 0, 64 lanes: lane L -> replica L>>2, quad L&3; lanes 4r..4r+3
// write replica r's 64B line contiguously in one burst (full-line, r11 lesson).
// Consumers poll ONLY replica (w&15): 32 pollers/line instead of 512.
// Poll = load + vmcnt(0) INSIDE the loop (r14 lesson: a load left outstanding
// past its compiler-visible live range clobbers reallocated VGPRs).

__global__ __launch_bounds__(BTH) __attribute__((amdgpu_waves_per_eu(2, 2)))
void lstm_kernel(const float* __restrict__ Wf, const float* __restrict__ bfv,
                 const float* __restrict__ Wb, const float* __restrict__ bbv,
                 const int* __restrict__ cidx,
                 ushort* __restrict__ hs16f, ushort* __restrict__ hs16b,
                 unsigned* __restrict__ mbx)
{
    const int wg   = blockIdx.x;
    const int dir  = wg >> 7;            // 0 fwd, 1 bwd
    const int w    = wg & (NWGD - 1);
    const int tid  = threadIdx.x;
    const int rg   = tid >> 5;           // unit_local 0..15
    const int ks   = tid & (KSL - 1);    // k-slice 0..31
    const int unit = w * UPW + rg;

    const float* W    = dir ? Wb : Wf;
    const float* bias = dir ? bbv : bfv;
    ushort* hs16      = dir ? hs16b : hs16f;
    unsigned* mbd     = mbx + (size_t)dir * 2 * MB_PAR;

    // h in LDS as fp16, double-buffered by step parity.
    __shared__ unsigned long long hl2_u64[2 * HL2SZ / 4];     // 8704 B
    // hstage[u]: {(s+1)<<16 | fp16 h bits} -- tagged, publish wave spins on it.
    __shared__ unsigned hstage[UPW];
    // Force 1 WG/CU (all 256 WGs co-resident across 256 CUs).
    __shared__ char force_one_wg[100 * 1024];
    if (tid == 0) ((volatile char*)force_one_wg)[0] = 0;
    ushort* hl2 = (ushort*)hl2_u64;

    // ---- one-time: weight slab -> 128 packed-fp16 VGPRs (4 gates x 32 half2)
    half2_t w2[4][KPT / 2];
    #pragma unroll
    for (int j = 0; j < 4; ++j) {
        const float* rbase = W + (size_t)(j * HH + unit) * SS + VV + ks * KPT;
        #pragma unroll
        for (int q = 0; q < KPT / 4; ++q) {
            const float4 wv = *reinterpret_cast<const float4*>(rbase + 4 * q);
            w2[j][2 * q]     = half2_t{(_Float16)wv.x, (_Float16)wv.y};
            w2[j][2 * q + 1] = half2_t{(_Float16)wv.z, (_Float16)wv.w};
        }
    }
    const float b_i = bias[0 * HH + unit];
    const float b_f = bias[1 * HH + unit];
    const float b_g = bias[2 * HH + unit];
    const float b_o = bias[3 * HH + unit];
    float creg = 0.0f;                                    // cell state (ks==0)

    // prestage h=0 (parity-0 buffer) + clear hstage tags
    for (int i = tid; i < HL2SZ / 4; i += BTH) hl2_u64[i] = 0ull;
    if (tid < UPW) hstage[tid] = 0u;

    // ---- gather pipeline: step-0 x-projection ----
    float gx0 = 0.f, gx1 = 0.f, gx2 = 0.f, gx3 = 0.f;
    if (ks == 0) {
        const int xt0 = cidx[dir ? (TT - 1) : 0];
        gx0 = W[(size_t)(0 * HH + unit) * SS + xt0];
        gx1 = W[(size_t)(1 * HH + unit) * SS + xt0];
        gx2 = W[(size_t)(2 * HH + unit) * SS + xt0];
        gx3 = W[(size_t)(3 * HH + unit) * SS + xt0];
    }
    __syncthreads();

    for (int s = 0; s < TT; ++s) {
        const int t = dir ? (TT - 1 - s) : s;

        // ---- recurrent dot: 4 gates x 64 k, fp16 h from buffer (s&1) ----
        float a0 = 0.f, a1 = 0.f, a2 = 0.f, a3 = 0.f;
        const ushort* hrow = hl2 + (s & 1) * HL2SZ + ks * HL2W;
        #pragma unroll
        for (int c = 0; c < KPT / 4; ++c) {
            const unsigned long long hv8 =
                *reinterpret_cast<const unsigned long long*>(hrow + c * 4);
            const half2_t ha = __builtin_bit_cast(half2_t, (unsigned)hv8);
            const half2_t hc = __builtin_bit_cast(half2_t, (unsigned)(hv8 >> 32));
            a0 = FDOT2(w2[0][2 * c], ha, a0); a0 = FDOT2(w2[0][2 * c + 1], hc, a0);
            a1 = FDOT2(w2[1][2 * c], ha, a1); a1 = FDOT2(w2[1][2 * c + 1], hc, a1);
            a2 = FDOT2(w2[2][2 * c], ha, a2); a2 = FDOT2(w2[2][2 * c + 1], hc, a2);
            a3 = FDOT2(w2[3][2 * c], ha, a3); a3 = FDOT2(w2[3][2 * c + 1], hc, a3);
        }

        // ---- merge-reduce: fold 4 accs into 1 (2 stages), then 3 xor stages.
        float sA = (ks & 1) ? a0 : a1, kA = (ks & 1) ? a1 : a0;
        float A  = kA + __shfl_xor(sA, 1, 64);
        float sB = (ks & 1) ? a2 : a3, kB = (ks & 1) ? a3 : a2;
        float B  = kB + __shfl_xor(sB, 1, 64);
        float sC = (ks & 2) ? A : B,  kC = (ks & 2) ? B : A;
        float C  = kC + __shfl_xor(sC, 2, 64);
        C += __shfl_xor(C, 4, 64);
        C += __shfl_xor(C, 8, 64);
        C += __shfl_xor(C, 16, 64);
        const float Cf = __shfl(C, 1, 32);
        const float Cg = __shfl(C, 2, 32);
        const float Co = __shfl(C, 3, 32);

        // ---- LSTM cell in-lane (ks==0): tagged hstage write only ----
        if (ks == 0) {
            const float gi = sigmoidf_(C  + gx0 + b_i);
            const float gf = sigmoidf_(Cf + gx1 + b_f);
            const float gg = tanhf(Cg + gx2 + b_g);
            const float go = sigmoidf_(Co + gx3 + b_o);
            creg = gf * creg + gi * gg;
            const float hv = go * tanhf(creg);
            const unsigned hbits =
                (unsigned)__builtin_bit_cast(ushort, (_Float16)hv);
            ((volatile unsigned*)hstage)[rg] = ((unsigned)(s + 1) << 16) | hbits;
        }

        // ---- publish: wave 0, lane L -> replica L>>2, quad L&3 ----
        if (tid < 64) {
            const unsigned tg = ((unsigned)(s + 1)) << 16;
            volatile unsigned* hp = hstage + 4 * (tid & 3);
            unsigned x0, x1, x2, x3;
            for (;;) {
                x0 = hp[0]; x1 = hp[1]; x2 = hp[2]; x3 = hp[3];
                if ((((x0 ^ tg) | (x1 ^ tg) | (x2 ^ tg) | (x3 ^ tg))
                     & 0xFFFF0000u) == 0u) break;
            }
            const uint4v pv = {(x0 & 0xFFFFu) | (x1 << 16),
                               (x2 & 0xFFFFu) | (x3 << 16),
                               0u, (unsigned)(s + 1)};
            unsigned* dst = mbd + (size_t)(s & 1) * MB_PAR
                          + (tid >> 2) * (NWGD * 16) + w * 16 + (tid & 3) * 4;
            asm volatile("global_store_dwordx4 %0, %1, off sc0 sc1"
                         :: "v"(dst), "v"(pv) : "memory");
        }

        // ---- poll+stage on own replica (load + vmcnt(0) each iteration) ----
        {
            const unsigned tag = (unsigned)(s + 1);
            const unsigned* src = mbd + (size_t)(s & 1) * MB_PAR
                                + (w & (NREP - 1)) * (NWGD * 16)
                                + (tid >> 2) * 16 + (tid & 3) * 4;
            uint4v v;
            for (;;) {
                asm volatile("global_load_dwordx4 %0, %1, off sc0 sc1\n\t"
                             "s_waitcnt vmcnt(0)"
                             : "=&v"(v) : "v"(src) : "memory");
                if (v.w == tag) break;
                __builtin_amdgcn_s_sleep(1);
            }
            const unsigned long long hv8 =
                (unsigned long long)v.x | ((unsigned long long)v.y << 32);

            // h history for out_gemm: one WG per step writes all 2048 fp16
            // (coalesced 8B/thread; fire-and-forget).
            if (w == (s & (NWGD - 1)))
                *reinterpret_cast<unsigned long long*>(
                    hs16 + (size_t)t * HH + 4 * tid) = hv8;

            if (s + 1 < TT) {
                // prefetch next step's one-hot gather (plain cached loads;
                // completes under stage+barrier+dot)
                if (ks == 0) {
                    const int xtn = cidx[dir ? (t - 1) : (t + 1)];
                    gx0 = W[(size_t)(0 * HH + unit) * SS + xtn];
                    gx1 = W[(size_t)(1 * HH + unit) * SS + xtn];
                    gx2 = W[(size_t)(2 * HH + unit) * SS + xtn];
                    gx3 = W[(size_t)(3 * HH + unit) * SS + xtn];
                }
                // stage units 4*tid..4*tid+3 into buffer ((s+1)&1)
                *reinterpret_cast<unsigned long long*>(
                    hl2 + ((s + 1) & 1) * HL2SZ + (tid >> 4) * HL2W
                        + (tid & 15) * 4) = hv8;
                LDS_BARRIER();
            }
        }
    }
    // drain all outstanding VMEM (publish/hs16 stores) before wave end.
    asm volatile("s_waitcnt vmcnt(0) lgkmcnt(0)" ::: "memory");
}

// out[t,v] = sum_j merged[t,j]*Wo[v,j] + bo[v],  merged = [hf16 | hb16], K=4096.
__global__ __launch_bounds__(256)
void out_gemm(const ushort* __restrict__ hs16f, const ushort* __restrict__ hs16b,
              const float* __restrict__ Wo, const float* __restrict__ bo,
              float* __restrict__ out)
{
    const int bn = blockIdx.x;
    const int bm = blockIdx.y;
    const int tid = threadIdx.x;
    const int tx = tid & 15, ty = tid >> 4;
    const int t0 = bm * 64, v0 = bn * 64;

    __shared__ float As[32][72];
    __shared__ float Bs[32][72];

    float acc[4][4] = {};

    const int rr = tid >> 2;
    const int kc = tid & 3;

    for (int kb = 0; kb < 2 * HH; kb += 32) {
        {
            const int k = kb + kc * 8;
            const ushort* asrc = (k < HH)
                ? (hs16f + (size_t)(t0 + rr) * HH + k)
                : (hs16b + (size_t)(t0 + rr) * HH + (k - HH));
            const uint4v av = *reinterpret_cast<const uint4v*>(asrc);
            const int kk = kc * 8;
            As[kk+0][rr]=h2f(av.x); As[kk+1][rr]=h2f(av.x>>16);
            As[kk+2][rr]=h2f(av.y); As[kk+3][rr]=h2f(av.y>>16);
            As[kk+4][rr]=h2f(av.z); As[kk+5][rr]=h2f(av.z>>16);
            As[kk+6][rr]=h2f(av.w); As[kk+7][rr]=h2f(av.w>>16);
            const float* bsrc = Wo + (size_t)(v0 + rr) * (2 * HH) + k;
            const float4 b0 = *reinterpret_cast<const float4*>(bsrc);
            const float4 b1 = *reinterpret_cast<const float4*>(bsrc + 4);
            Bs[kk+0][rr]=b0.x; Bs[kk+1][rr]=b0.y; Bs[kk+2][rr]=b0.z; Bs[kk+3][rr]=b0.w;
            Bs[kk+4][rr]=b1.x; Bs[kk+5][rr]=b1.y; Bs[kk+6][rr]=b1.z; Bs[kk+7][rr]=b1.w;
        }
        __syncthreads();
        #pragma unroll 8
        for (int kk = 0; kk < 32; ++kk) {
            const float4 av = *reinterpret_cast<const float4*>(&As[kk][ty * 4]);
            const float4 bv = *reinterpret_cast<const float4*>(&Bs[kk][tx * 4]);
            const float a[4] = {av.x, av.y, av.z, av.w};
            const float b[4] = {bv.x, bv.y, bv.z, bv.w};
            #pragma unroll
            for (int i2 = 0; i2 < 4; ++i2)
                #pragma unroll
                for (int j2 = 0; j2 < 4; ++j2)
                    acc[i2][j2] = fmaf(a[i2], b[j2], acc[i2][j2]);
        }
        __syncthreads();
    }
    #pragma unroll
    for (int i2 = 0; i2 < 4; ++i2) {
        const int t = t0 + ty * 4 + i2;
        #pragma unroll
        for (int j2 = 0; j2 < 4; ++j2) {
            const int v = v0 + tx * 4 + j2;
            out[(size_t)t * VV + v] = acc[i2][j2] + bo[v];
        }
    }
}

extern "C" void kernel_launch(void* const* d_in, const int* in_sizes, int n_in,
                              void* d_out, int out_size, void* d_ws, size_t ws_size,
                              hipStream_t stream)
{
    (void)in_sizes; (void)n_in; (void)out_size; (void)ws_size;

    const float* Wf  = (const float*)d_in[0];
    const float* bfv = (const float*)d_in[1];
    const float* Wb  = (const float*)d_in[2];
    const float* bbv = (const float*)d_in[3];
    const float* Wo  = (const float*)d_in[4];
    const float* bo  = (const float*)d_in[5];
    const int*   cid = (const int*)d_in[6];
    float* out = (float*)d_out;

    unsigned char* ws = (unsigned char*)d_ws;
    unsigned* mbx = (unsigned*)ws;                          // 512 KiB mailbox
    ushort* hs16f = (ushort*)(ws + (1 << 20));              // [T][H] fp16, 8 MiB
    ushort* hs16b = hs16f + (size_t)TT * HH;                // [T][H] fp16, 8 MiB

    // Re-zero mailbox tags every launch (ws poisoned once, never restored)
    (void)hipMemsetAsync(mbx, 0, 2 * 2 * MB_PAR * 4, stream);

    lstm_kernel<<<dim3(2 * NWGD), dim3(BTH), 0, stream>>>(Wf, bfv, Wb, bbv, cid,
                                                          hs16f, hs16b, mbx);
    out_gemm<<<dim3(VV / 64, TT / 64), dim3(256), 0, stream>>>(hs16f, hs16b,
                                                               Wo, bo, out);
}

// Round 16
// 6035.652 us; speedup vs baseline: 1.0345x; 1.0345x over previous
//
#include <hip/hip_runtime.h>
#include <math.h>

// Problem dims
#define TT 2048
#define VV 1024
#define HH 2048
#define SS (VV + HH)        // 3072: row stride of Wf_w / Wb_w

// Geometry: 256 WGs x 512 threads, one WG per CU (forced by LDS pad).
#define NWGD 128            // workgroups per direction
#define BTH  512            // threads per workgroup (8 waves = 2/EU)
#define UPW  16             // hidden units per wg
#define KSL  32             // k-slices per unit
#define KPT  64             // k-elements per thread (per gate row)

#define HL2W 68             // ushorts per h-row (136B: 2-way bank alias max)

static_assert(NWGD * UPW == HH, "unit coverage");
static_assert(UPW * KSL == BTH, "thread coverage");
static_assert(KSL * KPT == HH, "k coverage");

typedef _Float16 half2_t __attribute__((ext_vector_type(2)));
typedef unsigned uint4v  __attribute__((ext_vector_type(4)));

#if defined(__has_builtin)
#if __has_builtin(__builtin_amdgcn_fdot2)
#define FDOT2(w, h, c) __builtin_amdgcn_fdot2((w), (h), (c), false)
#endif
#endif
#ifndef FDOT2
__device__ __forceinline__ float fdot2_asm(half2_t w, half2_t h, float c) {
    float r = c;
    asm volatile("v_dot2_f32_f16 %0, %1, %2, %0" : "+v"(r) : "v"(w), "v"(h));
    return r;
}
#define FDOT2(w, h, c) fdot2_asm((w), (h), (c))
#endif

__device__ __forceinline__ float sigmoidf_(float x) {
    return 1.0f / (1.0f + __expf(-x));
}

// Mailbox: [dir][parity][producer p<128][quad q<4] of 16B:
//   { h(4q..4q+3) as 4 x fp16 in w0,w1 ; 0 ; tag = s+1 }
// Publish: 4 packer lanes fire one 64B line in one burst (r11 lesson).
// Consume: SENTINEL polling -- 128 threads poll only quad-0's 16B (4x less
// poll traffic than r10's 512x16B; aggregate ~1.3 TB/s vs ~5 TB/s), then
// verify-read the full 64B line until all 4 quad tags match (the quads are
// stored in one wave burst, so this converges immediately; tags make partial
// visibility safe). Loads always drain vmcnt(0) in-loop (r14 lesson).

__global__ __launch_bounds__(BTH) __attribute__((amdgpu_waves_per_eu(2, 2)))
void lstm_kernel(const float* __restrict__ Wf, const float* __restrict__ bfv,
                 const float* __restrict__ Wb, const float* __restrict__ bbv,
                 const int* __restrict__ cidx,
                 float* __restrict__ hsf, float* __restrict__ hsb,
                 unsigned* __restrict__ mbx)
{
    const int wg   = blockIdx.x;
    const int dir  = wg >> 7;            // 0 fwd, 1 bwd
    const int w    = wg & (NWGD - 1);
    const int tid  = threadIdx.x;
    const int rg   = tid >> 5;           // unit_local 0..15
    const int ks   = tid & (KSL - 1);    // k-slice 0..31
    const int unit = w * UPW + rg;

    const float* W    = dir ? Wb : Wf;
    const float* bias = dir ? bbv : bfv;
    float* hs         = dir ? hsb : hsf;
    unsigned* mbd     = mbx + (size_t)dir * (2 * NWGD * 16);  // u32 units

    // h in LDS as fp16, rows of 68 ushorts (136B): ds_read_b64 2-way max.
    __shared__ unsigned long long hl2_u64[(KSL * HL2W) / 4];  // 4352 B
    __shared__ ushort hstage[UPW];
    // Force 1 WG/CU (all 256 WGs co-resident across 256 CUs).
    __shared__ char force_one_wg[100 * 1024];
    if (tid == 0) ((volatile char*)force_one_wg)[0] = 0;
    ushort* hl2 = (ushort*)hl2_u64;

    // ---- one-time: weight slab -> 128 packed-fp16 VGPRs (4 gates x 32 half2)
    half2_t w2[4][KPT / 2];
    #pragma unroll
    for (int j = 0; j < 4; ++j) {
        const float* rbase = W + (size_t)(j * HH + unit) * SS + VV + ks * KPT;
        #pragma unroll
        for (int q = 0; q < KPT / 4; ++q) {
            const float4 wv = *reinterpret_cast<const float4*>(rbase + 4 * q);
            w2[j][2 * q]     = half2_t{(_Float16)wv.x, (_Float16)wv.y};
            w2[j][2 * q + 1] = half2_t{(_Float16)wv.z, (_Float16)wv.w};
        }
    }
    const float b_i = bias[0 * HH + unit];
    const float b_f = bias[1 * HH + unit];
    const float b_g = bias[2 * HH + unit];
    const float b_o = bias[3 * HH + unit];
    float creg = 0.0f;                                    // cell state (ks==0)

    // prestage h=0 for step 0
    for (int i = tid; i < (KSL * HL2W) / 4; i += BTH) hl2_u64[i] = 0ull;
    __syncthreads();

    for (int s = 0; s < TT; ++s) {
        const int t  = dir ? (TT - 1 - s) : s;
        const int xt = cidx[t];
        // one-hot input projection: exact fp32 gather (ks==0 lanes only)
        float gx0 = 0.f, gx1 = 0.f, gx2 = 0.f, gx3 = 0.f;
        if (ks == 0) {
            gx0 = W[(size_t)(0 * HH + unit) * SS + xt];
            gx1 = W[(size_t)(1 * HH + unit) * SS + xt];
            gx2 = W[(size_t)(2 * HH + unit) * SS + xt];
            gx3 = W[(size_t)(3 * HH + unit) * SS + xt];
        }

        // ---- recurrent dot: 4 gates x 64 k, fp16 h from LDS (b64 reads) ----
        float a0 = 0.f, a1 = 0.f, a2 = 0.f, a3 = 0.f;
        const ushort* hrow = hl2 + ks * HL2W;
        #pragma unroll
        for (int c = 0; c < KPT / 4; ++c) {
            const unsigned long long hv8 =
                *reinterpret_cast<const unsigned long long*>(hrow + c * 4);
            const half2_t ha = __builtin_bit_cast(half2_t, (unsigned)hv8);
            const half2_t hc = __builtin_bit_cast(half2_t, (unsigned)(hv8 >> 32));
            a0 = FDOT2(w2[0][2 * c], ha, a0); a0 = FDOT2(w2[0][2 * c + 1], hc, a0);
            a1 = FDOT2(w2[1][2 * c], ha, a1); a1 = FDOT2(w2[1][2 * c + 1], hc, a1);
            a2 = FDOT2(w2[2][2 * c], ha, a2); a2 = FDOT2(w2[2][2 * c + 1], hc, a2);
            a3 = FDOT2(w2[3][2 * c], ha, a3); a3 = FDOT2(w2[3][2 * c + 1], hc, a3);
        }

        // ---- merge-reduce: fold 4 accs into 1 (2 stages), then 3 xor stages.
        float sA = (ks & 1) ? a0 : a1, kA = (ks & 1) ? a1 : a0;
        float A  = kA + __shfl_xor(sA, 1, 64);
        float sB = (ks & 1) ? a2 : a3, kB = (ks & 1) ? a3 : a2;
        float B  = kB + __shfl_xor(sB, 1, 64);
        float sC = (ks & 2) ? A : B,  kC = (ks & 2) ? B : A;
        float C  = kC + __shfl_xor(sC, 2, 64);
        C += __shfl_xor(C, 4, 64);
        C += __shfl_xor(C, 8, 64);
        C += __shfl_xor(C, 16, 64);
        const float Cf = __shfl(C, 1, 32);
        const float Cg = __shfl(C, 2, 32);
        const float Co = __shfl(C, 3, 32);

        // ---- LSTM cell in-lane (ks==0): h -> hs (plain) + hstage (fp16) ----
        if (ks == 0) {
            const float gi = sigmoidf_(C  + gx0 + b_i);
            const float gf = sigmoidf_(Cf + gx1 + b_f);
            const float gg = tanhf(Cg + gx2 + b_g);
            const float go = sigmoidf_(Co + gx3 + b_o);
            creg = gf * creg + gi * gg;
            const float hv = go * tanhf(creg);
            hs[(size_t)t * HH + unit] = hv;               // for out_gemm
            hstage[rg] = __builtin_bit_cast(ushort, (_Float16)hv);
        }
        __syncthreads();   // A: dot-reads of hl2 done; hstage populated

        // ---- publish: 4 packer threads, one 64B line in one burst ----
        if (tid < 4) {
            const unsigned w0 = (unsigned)hstage[4 * tid] |
                                ((unsigned)hstage[4 * tid + 1] << 16);
            const unsigned w1 = (unsigned)hstage[4 * tid + 2] |
                                ((unsigned)hstage[4 * tid + 3] << 16);
            const uint4v pv = {w0, w1, 0u, (unsigned)(s + 1)};
            unsigned* dst = mbd + (size_t)(s & 1) * (NWGD * 16) + w * 16 + tid * 4;
            asm volatile("global_store_dwordx4 %0, %1, off sc0 sc1"
                         :: "v"(dst), "v"(pv) : "memory");
        }

        if (s + 1 < TT) {
            // ---- sentinel poll: thread p (<128) polls producer p's quad-0 ----
            if (tid < NWGD) {
                const unsigned tag = (unsigned)(s + 1);
                const unsigned* line = mbd + (size_t)(s & 1) * (NWGD * 16)
                                     + tid * 16;
                uint4v v0;
                for (;;) {
                    asm volatile("global_load_dwordx4 %0, %1, off sc0 sc1\n\t"
                                 "s_waitcnt vmcnt(0)"
                                 : "=&v"(v0) : "v"(line) : "memory");
                    if (v0.w == tag) break;
                    __builtin_amdgcn_s_sleep(1);
                }
                // verify-read full 64B until all 4 quad tags match
                uint4v q0, q1, q2, q3;
                for (;;) {
                    asm volatile(
                        "global_load_dwordx4 %0, %4, off sc0 sc1\n\t"
                        "global_load_dwordx4 %1, %4, off offset:16 sc0 sc1\n\t"
                        "global_load_dwordx4 %2, %4, off offset:32 sc0 sc1\n\t"
                        "global_load_dwordx4 %3, %4, off offset:48 sc0 sc1\n\t"
                        "s_waitcnt vmcnt(0)"
                        : "=&v"(q0), "=&v"(q1), "=&v"(q2), "=&v"(q3)
                        : "v"(line) : "memory");
                    if ((q0.w == tag) & (q1.w == tag) &
                        (q2.w == tag) & (q3.w == tag)) break;
                    __builtin_amdgcn_s_sleep(1);
                }
                // stage units 16p..16p+15: row p>>2, ushort col (p&3)*16
                unsigned long long* d64 = reinterpret_cast<unsigned long long*>(
                    hl2 + (tid >> 2) * HL2W + (tid & 3) * 16);
                d64[0] = (unsigned long long)q0.x | ((unsigned long long)q0.y << 32);
                d64[1] = (unsigned long long)q1.x | ((unsigned long long)q1.y << 32);
                d64[2] = (unsigned long long)q2.x | ((unsigned long long)q2.y << 32);
                d64[3] = (unsigned long long)q3.x | ((unsigned long long)q3.y << 32);
            }
            __syncthreads();   // B: hl2 ready for next dot
        }
    }
}

// out[t,v] = sum_j merged[t,j]*Wo[v,j] + bo[v],  merged = [hf | hb], K = 4096.
__global__ __launch_bounds__(256)
void out_gemm(const float* __restrict__ hsf, const float* __restrict__ hsb,
              const float* __restrict__ Wo, const float* __restrict__ bo,
              float* __restrict__ out)
{
    const int bn = blockIdx.x;
    const int bm = blockIdx.y;
    const int tid = threadIdx.x;
    const int tx = tid & 15, ty = tid >> 4;
    const int t0 = bm * 64, v0 = bn * 64;

    __shared__ float As[32][72];
    __shared__ float Bs[32][72];

    float acc[4][4] = {};

    const int rr = tid >> 2;
    const int kc = tid & 3;

    for (int kb = 0; kb < 2 * HH; kb += 32) {
        {
            const int k = kb + kc * 8;
            const float* asrc = (k < HH) ? (hsf + (size_t)(t0 + rr) * HH + k)
                                         : (hsb + (size_t)(t0 + rr) * HH + (k - HH));
            const float4 a0 = *reinterpret_cast<const float4*>(asrc);
            const float4 a1 = *reinterpret_cast<const float4*>(asrc + 4);
            const int kk = kc * 8;
            As[kk+0][rr]=a0.x; As[kk+1][rr]=a0.y; As[kk+2][rr]=a0.z; As[kk+3][rr]=a0.w;
            As[kk+4][rr]=a1.x; As[kk+5][rr]=a1.y; As[kk+6][rr]=a1.z; As[kk+7][rr]=a1.w;
            const float* bsrc = Wo + (size_t)(v0 + rr) * (2 * HH) + k;
            const float4 b0 = *reinterpret_cast<const float4*>(bsrc);
            const float4 b1 = *reinterpret_cast<const float4*>(bsrc + 4);
            Bs[kk+0][rr]=b0.x; Bs[kk+1][rr]=b0.y; Bs[kk+2][rr]=b0.z; Bs[kk+3][rr]=b0.w;
            Bs[kk+4][rr]=b1.x; Bs[kk+5][rr]=b1.y; Bs[kk+6][rr]=b1.z; Bs[kk+7][rr]=b1.w;
        }
        __syncthreads();
        #pragma unroll 8
        for (int kk = 0; kk < 32; ++kk) {
            const float4 av = *reinterpret_cast<const float4*>(&As[kk][ty * 4]);
            const float4 bv = *reinterpret_cast<const float4*>(&Bs[kk][tx * 4]);
            const float a[4] = {av.x, av.y, av.z, av.w};
            const float b[4] = {bv.x, bv.y, bv.z, bv.w};
            #pragma unroll
            for (int i2 = 0; i2 < 4; ++i2)
                #pragma unroll
                for (int j2 = 0; j2 < 4; ++j2)
                    acc[i2][j2] = fmaf(a[i2], b[j2], acc[i2][j2]);
        }
        __syncthreads();
    }
    #pragma unroll
    for (int i2 = 0; i2 < 4; ++i2) {
        const int t = t0 + ty * 4 + i2;
        #pragma unroll
        for (int j2 = 0; j2 < 4; ++j2) {
            const int v = v0 + tx * 4 + j2;
            out[(size_t)t * VV + v] = acc[i2][j2] + bo[v];
        }
    }
}

extern "C" void kernel_launch(void* const* d_in, const int* in_sizes, int n_in,
                              void* d_out, int out_size, void* d_ws, size_t ws_size,
                              hipStream_t stream)
{
    (void)in_sizes; (void)n_in; (void)out_size; (void)ws_size;

    const float* Wf  = (const float*)d_in[0];
    const float* bfv = (const float*)d_in[1];
    const float* Wb  = (const float*)d_in[2];
    const float* bbv = (const float*)d_in[3];
    const float* Wo  = (const float*)d_in[4];
    const float* bo  = (const float*)d_in[5];
    const int*   cid = (const int*)d_in[6];
    float* out = (float*)d_out;

    unsigned char* ws = (unsigned char*)d_ws;
    unsigned* mbx = (unsigned*)ws;                         // 32 KiB mailbox
    float* hsf = (float*)(ws + 65536);                     // [T][H] fp32, 16 MiB
    float* hsb = hsf + (size_t)TT * HH;                    // [T][H] fp32, 16 MiB

    // Re-zero mailbox tags every launch (ws poisoned once, never restored)
    (void)hipMemsetAsync(mbx, 0, 32768, stream);

    lstm_kernel<<<dim3(2 * NWGD), dim3(BTH), 0, stream>>>(Wf, bfv, Wb, bbv, cid,
                                                          hsf, hsb, mbx);
    out_gemm<<<dim3(VV / 64, TT / 64), dim3(256), 0, stream>>>(hsf, hsb, Wo, bo, out);
}

// Round 17
// 5665.099 us; speedup vs baseline: 1.1022x; 1.0654x over previous
//
#include <hip/hip_runtime.h>
#include <math.h>

// ============================================================================
// CHAMPION RESTORE (round-10 kernel, measured 5.48 ms lstm / 5.71 ms total).
// Exchange structure: per-step tagged mailbox, 4x16B full-line publish,
// 512-thread fused poll+stage with vmcnt(0) in-loop.
// Five structural variants (r11-r16) were neutral or worse -> latency floor:
// step = compute 0.65us + store visibility 0.5 + detect 0.6 + stage/barriers
// 0.4 + straggler skew 0.4 = ~2.6us, x2048 = 5.3ms (measured 5.48).
// ============================================================================

// Problem dims
#define TT 2048
#define VV 1024
#define HH 2048
#define SS (VV + HH)        // 3072: row stride of Wf_w / Wb_w

// Geometry: 256 WGs x 512 threads, one WG per CU (forced by LDS pad).
#define NWGD 128            // workgroups per direction
#define BTH  512            // threads per workgroup (8 waves = 2/EU)
#define UPW  16             // hidden units per wg
#define KSL  32             // k-slices per unit
#define KPT  64             // k-elements per thread (per gate row)

static_assert(NWGD * UPW == HH, "unit coverage");
static_assert(UPW * KSL == BTH, "thread coverage");
static_assert(KSL * KPT == HH, "k coverage");

typedef _Float16 half2_t __attribute__((ext_vector_type(2)));
typedef unsigned uint4v  __attribute__((ext_vector_type(4)));

#if defined(__has_builtin)
#if __has_builtin(__builtin_amdgcn_fdot2)
#define FDOT2(w, h, c) __builtin_amdgcn_fdot2((w), (h), (c), false)
#endif
#endif
#ifndef FDOT2
__device__ __forceinline__ float fdot2_asm(half2_t w, half2_t h, float c) {
    float r = c;
    asm volatile("v_dot2_f32_f16 %0, %1, %2, %0" : "+v"(r) : "v"(w), "v"(h));
    return r;
}
#define FDOT2(w, h, c) fdot2_asm((w), (h), (c))
#endif

__device__ __forceinline__ float sigmoidf_(float x) {
    return 1.0f / (1.0f + __expf(-x));
}

// Mailbox: [dir][parity][producer p<128][quad q<4] of 16B:
//   { h(4q..4q+3) as 4 x fp16 in w0,w1 ; 0 ; tag = s+1 }
// One dwordx4 = data + validity in a single L3 transaction.

__global__ __launch_bounds__(BTH) __attribute__((amdgpu_waves_per_eu(2, 2)))
void lstm_kernel(const float* __restrict__ Wf, const float* __restrict__ bfv,
                 const float* __restrict__ Wb, const float* __restrict__ bbv,
                 const int* __restrict__ cidx,
                 float* __restrict__ hsf, float* __restrict__ hsb,
                 unsigned* __restrict__ mbx)
{
    const int wg   = blockIdx.x;
    const int dir  = wg >> 7;            // 0 fwd, 1 bwd
    const int w    = wg & (NWGD - 1);
    const int tid  = threadIdx.x;
    const int rg   = tid >> 5;           // unit_local 0..15
    const int ks   = tid & (KSL - 1);    // k-slice 0..31
    const int unit = w * UPW + rg;

    const float* W    = dir ? Wb : Wf;
    const float* bias = dir ? bbv : bfv;
    float* hs         = dir ? hsb : hsf;
    unsigned* mbd     = mbx + (size_t)dir * (2 * NWGD * 16);  // u32 units

    // h in LDS as fp16, rows of 68 ushorts (136B): ds_read_b64 2-way max.
    __shared__ unsigned long long hl2_u64[(KSL * 68) / 4];    // 4352 B
    __shared__ ushort hstage[UPW];
    // Force 1 WG/CU (all 256 WGs co-resident across 256 CUs).
    __shared__ char force_one_wg[100 * 1024];
    if (tid == 0) ((volatile char*)force_one_wg)[0] = 0;
    ushort* hl2 = (ushort*)hl2_u64;

    // ---- one-time: weight slab -> 128 packed-fp16 VGPRs (4 gates x 32 half2)
    half2_t w2[4][KPT / 2];
    #pragma unroll
    for (int j = 0; j < 4; ++j) {
        const float* rbase = W + (size_t)(j * HH + unit) * SS + VV + ks * KPT;
        #pragma unroll
        for (int q = 0; q < KPT / 4; ++q) {
            const float4 wv = *reinterpret_cast<const float4*>(rbase + 4 * q);
            w2[j][2 * q]     = half2_t{(_Float16)wv.x, (_Float16)wv.y};
            w2[j][2 * q + 1] = half2_t{(_Float16)wv.z, (_Float16)wv.w};
        }
    }
    const float b_i = bias[0 * HH + unit];
    const float b_f = bias[1 * HH + unit];
    const float b_g = bias[2 * HH + unit];
    const float b_o = bias[3 * HH + unit];
    float creg = 0.0f;                                    // cell state (ks==0)

    // prestage h=0 for step 0
    for (int i = tid; i < (KSL * 68) / 4; i += BTH) hl2_u64[i] = 0ull;
    __syncthreads();

    for (int s = 0; s < TT; ++s) {
        const int t  = dir ? (TT - 1 - s) : s;
        const int xt = cidx[t];
        // one-hot input projection: exact fp32 gather (ks==0 lanes only)
        float gx0 = 0.f, gx1 = 0.f, gx2 = 0.f, gx3 = 0.f;
        if (ks == 0) {
            gx0 = W[(size_t)(0 * HH + unit) * SS + xt];
            gx1 = W[(size_t)(1 * HH + unit) * SS + xt];
            gx2 = W[(size_t)(2 * HH + unit) * SS + xt];
            gx3 = W[(size_t)(3 * HH + unit) * SS + xt];
        }

        // ---- recurrent dot: 4 gates x 64 k, fp16 h from LDS (b64 reads) ----
        float a0 = 0.f, a1 = 0.f, a2 = 0.f, a3 = 0.f;
        const ushort* hrow = hl2 + ks * 68;
        #pragma unroll
        for (int c = 0; c < KPT / 4; ++c) {
            const unsigned long long hv8 =
                *reinterpret_cast<const unsigned long long*>(hrow + c * 4);
            const half2_t ha = __builtin_bit_cast(half2_t, (unsigned)hv8);
            const half2_t hc = __builtin_bit_cast(half2_t, (unsigned)(hv8 >> 32));
            a0 = FDOT2(w2[0][2 * c], ha, a0); a0 = FDOT2(w2[0][2 * c + 1], hc, a0);
            a1 = FDOT2(w2[1][2 * c], ha, a1); a1 = FDOT2(w2[1][2 * c + 1], hc, a1);
            a2 = FDOT2(w2[2][2 * c], ha, a2); a2 = FDOT2(w2[2][2 * c + 1], hc, a2);
            a3 = FDOT2(w2[3][2 * c], ha, a3); a3 = FDOT2(w2[3][2 * c + 1], hc, a3);
        }

        // ---- merge-reduce: fold 4 accs into 1 (2 stages), then 3 xor stages.
        float sA = (ks & 1) ? a0 : a1, kA = (ks & 1) ? a1 : a0;
        float A  = kA + __shfl_xor(sA, 1, 64);
        float sB = (ks & 1) ? a2 : a3, kB = (ks & 1) ? a3 : a2;
        float B  = kB + __shfl_xor(sB, 1, 64);
        float sC = (ks & 2) ? A : B,  kC = (ks & 2) ? B : A;
        float C  = kC + __shfl_xor(sC, 2, 64);
        C += __shfl_xor(C, 4, 64);
        C += __shfl_xor(C, 8, 64);
        C += __shfl_xor(C, 16, 64);
        const float Cf = __shfl(C, 1, 32);
        const float Cg = __shfl(C, 2, 32);
        const float Co = __shfl(C, 3, 32);

        // ---- LSTM cell in-lane (ks==0): h -> hs (plain) + hstage (fp16) ----
        if (ks == 0) {
            const float gi = sigmoidf_(C  + gx0 + b_i);
            const float gf = sigmoidf_(Cf + gx1 + b_f);
            const float gg = tanhf(Cg + gx2 + b_g);
            const float go = sigmoidf_(Co + gx3 + b_o);
            creg = gf * creg + gi * gg;
            const float hv = go * tanhf(creg);
            hs[(size_t)t * HH + unit] = hv;               // for out_gemm
            hstage[rg] = __builtin_bit_cast(ushort, (_Float16)hv);
        }
        __syncthreads();   // A: dot-reads of hl2 done; hstage populated

        // ---- publish: 4 packer threads, one tagged dwordx4 each (one 64B
        // line in one burst; r11 lesson: sub-line sc-stores write-amplify) ----
        if (tid < 4) {
            const unsigned w0 = (unsigned)hstage[4 * tid] |
                                ((unsigned)hstage[4 * tid + 1] << 16);
            const unsigned w1 = (unsigned)hstage[4 * tid + 2] |
                                ((unsigned)hstage[4 * tid + 3] << 16);
            const uint4v pv = {w0, w1, 0u, (unsigned)(s + 1)};
            unsigned* dst = mbd + (size_t)(s & 1) * (NWGD * 16) + w * 16 + tid * 4;
            asm volatile("global_store_dwordx4 %0, %1, off sc0 sc1"
                         :: "v"(dst), "v"(pv) : "memory");
        }

        if (s + 1 < TT) {
            // ---- poll+stage: thread tid owns producer tid>>2, quad tid&3;
            // load + vmcnt(0) inside the loop (r14 lesson: never leave an
            // asm load outstanding past its compiler-visible live range) ----
            const unsigned tag = (unsigned)(s + 1);
            const unsigned* src = mbd + (size_t)(s & 1) * (NWGD * 16)
                                + (tid >> 2) * 16 + (tid & 3) * 4;
            uint4v v;
            for (;;) {
                asm volatile("global_load_dwordx4 %0, %1, off sc0 sc1\n\t"
                             "s_waitcnt vmcnt(0)"
                             : "=&v"(v) : "v"(src) : "memory");
                if (v.w == tag) break;
                __builtin_amdgcn_s_sleep(1);
            }
            const unsigned long long hv8 =
                (unsigned long long)v.x | ((unsigned long long)v.y << 32);
            // k0 = 4*tid: row = tid>>4, col(ushort) = (tid&15)*4
            *reinterpret_cast<unsigned long long*>(
                hl2 + (tid >> 4) * 68 + (tid & 15) * 4) = hv8;
            __syncthreads();   // B: hl2 ready for next dot
        }
    }
}

// out[t,v] = sum_j merged[t,j]*Wo[v,j] + bo[v],  merged = [hf | hb], K = 4096.
__global__ __launch_bounds__(256)
void out_gemm(const float* __restrict__ hsf, const float* __restrict__ hsb,
              const float* __restrict__ Wo, const float* __restrict__ bo,
              float* __restrict__ out)
{
    const int bn = blockIdx.x;
    const int bm = blockIdx.y;
    const int tid = threadIdx.x;
    const int tx = tid & 15, ty = tid >> 4;
    const int t0 = bm * 64, v0 = bn * 64;

    __shared__ float As[32][72];
    __shared__ float Bs[32][72];

    float acc[4][4] = {};

    const int rr = tid >> 2;
    const int kc = tid & 3;

    for (int kb = 0; kb < 2 * HH; kb += 32) {
        {
            const int k = kb + kc * 8;
            const float* asrc = (k < HH) ? (hsf + (size_t)(t0 + rr) * HH + k)
                                         : (hsb + (size_t)(t0 + rr) * HH + (k - HH));
            const float4 a0 = *reinterpret_cast<const float4*>(asrc);
            const float4 a1 = *reinterpret_cast<const float4*>(asrc + 4);
            const int kk = kc * 8;
            As[kk+0][rr]=a0.x; As[kk+1][rr]=a0.y; As[kk+2][rr]=a0.z; As[kk+3][rr]=a0.w;
            As[kk+4][rr]=a1.x; As[kk+5][rr]=a1.y; As[kk+6][rr]=a1.z; As[kk+7][rr]=a1.w;
            const float* bsrc = Wo + (size_t)(v0 + rr) * (2 * HH) + k;
            const float4 b0 = *reinterpret_cast<const float4*>(bsrc);
            const float4 b1 = *reinterpret_cast<const float4*>(bsrc + 4);
            Bs[kk+0][rr]=b0.x; Bs[kk+1][rr]=b0.y; Bs[kk+2][rr]=b0.z; Bs[kk+3][rr]=b0.w;
            Bs[kk+4][rr]=b1.x; Bs[kk+5][rr]=b1.y; Bs[kk+6][rr]=b1.z; Bs[kk+7][rr]=b1.w;
        }
        __syncthreads();
        #pragma unroll 8
        for (int kk = 0; kk < 32; ++kk) {
            const float4 av = *reinterpret_cast<const float4*>(&As[kk][ty * 4]);
            const float4 bv = *reinterpret_cast<const float4*>(&Bs[kk][tx * 4]);
            const float a[4] = {av.x, av.y, av.z, av.w};
            const float b[4] = {bv.x, bv.y, bv.z, bv.w};
            #pragma unroll
            for (int i2 = 0; i2 < 4; ++i2)
                #pragma unroll
                for (int j2 = 0; j2 < 4; ++j2)
                    acc[i2][j2] = fmaf(a[i2], b[j2], acc[i2][j2]);
        }
        __syncthreads();
    }
    #pragma unroll
    for (int i2 = 0; i2 < 4; ++i2) {
        const int t = t0 + ty * 4 + i2;
        #pragma unroll
        for (int j2 = 0; j2 < 4; ++j2) {
            const int v = v0 + tx * 4 + j2;
            out[(size_t)t * VV + v] = acc[i2][j2] + bo[v];
        }
    }
}

extern "C" void kernel_launch(void* const* d_in, const int* in_sizes, int n_in,
                              void* d_out, int out_size, void* d_ws, size_t ws_size,
                              hipStream_t stream)
{
    (void)in_sizes; (void)n_in; (void)out_size; (void)ws_size;

    const float* Wf  = (const float*)d_in[0];
    const float* bfv = (const float*)d_in[1];
    const float* Wb  = (const float*)d_in[2];
    const float* bbv = (const float*)d_in[3];
    const float* Wo  = (const float*)d_in[4];
    const float* bo  = (const float*)d_in[5];
    const int*   cid = (const int*)d_in[6];
    float* out = (float*)d_out;

    unsigned char* ws = (unsigned char*)d_ws;
    unsigned* mbx = (unsigned*)ws;                         // 32 KiB mailbox
    float* hsf = (float*)(ws + 65536);                     // [T][H] fp32, 16 MiB
    float* hsb = hsf + (size_t)TT * HH;                    // [T][H] fp32, 16 MiB

    // Re-zero mailbox tags every launch (ws poisoned once, never restored)
    (void)hipMemsetAsync(mbx, 0, 32768, stream);

    lstm_kernel<<<dim3(2 * NWGD), dim3(BTH), 0, stream>>>(Wf, bfv, Wb, bbv, cid,
                                                          hsf, hsb, mbx);
    out_gemm<<<dim3(VV / 64, TT / 64), dim3(256), 0, stream>>>(hsf, hsb, Wo, bo, out);
}